// Round 10
// baseline (1204.205 us; speedup 1.0000x reference)
//
#include <hip/hip_runtime.h>
#include <hip/hip_cooperative_groups.h>

namespace cg = cooperative_groups;

#define N_NODES 100000
#define N_EDGES 1600000
#define DIM 128
#define NCLS 64
#define NG 128
#define BN_EPS 1e-5f
#define COOP_BLOCKS 512
#define GSZ (COOP_BLOCKS * 256)

typedef __attribute__((ext_vector_type(8))) short s16x8;
typedef __attribute__((ext_vector_type(4))) float f32x4;
#define MFMA_BF16 __builtin_amdgcn_mfma_f32_16x16x32_bf16

// f32 -> bf16 RNE
__device__ __forceinline__ unsigned short f2b(float x) {
    unsigned u = __float_as_uint(x);
    return (unsigned short)((u + 0x7FFFu + ((u >> 16) & 1u)) >> 16);
}
__device__ __forceinline__ float b2f(unsigned short s) {
    return __uint_as_float(((unsigned)s) << 16);
}
__device__ __forceinline__ float4 bexp4(ushort4 u) {
    float4 f;
    f.x = b2f(u.x); f.y = b2f(u.y); f.z = b2f(u.z); f.w = b2f(u.w);
    return f;
}

// split 8 f32 into bf16 hi + bf16 lo (truncation)
__device__ __forceinline__ void f2hl8(float4 v0, float4 v1, s16x8& h8, s16x8& l8) {
    float vv[8] = {v0.x, v0.y, v0.z, v0.w, v1.x, v1.y, v1.z, v1.w};
#pragma unroll
    for (int i = 0; i < 8; ++i) {
        unsigned u = __float_as_uint(vv[i]);
        short h = (short)(u >> 16);
        float r = vv[i] - __uint_as_float(u & 0xFFFF0000u);
        short l = (short)(__float_as_uint(r) >> 16);
        h8[i] = h;
        l8[i] = l;
    }
}

// ================= cooperative prologue: zero|wprep|cvt -> hist -> scan -> scatter
__global__ __launch_bounds__(256, 4) void k_coop(
        const float* __restrict__ Wl0, const float* __restrict__ Wr0,
        const float* __restrict__ Wl1, const float* __restrict__ Wr1,
        const float* __restrict__ Wp,
        short* __restrict__ fWl0h, short* __restrict__ fWl0l,
        short* __restrict__ fWr0h, short* __restrict__ fWr0l,
        short* __restrict__ fWl1h, short* __restrict__ fWl1l,
        short* __restrict__ fWr1h, short* __restrict__ fWr1l,
        short* __restrict__ fWph, short* __restrict__ fWpl,
        const float* __restrict__ x, unsigned short* __restrict__ x_bf,
        const int* __restrict__ src, const int* __restrict__ dst,
        int* __restrict__ cnt, int* __restrict__ rowptr,
        int* __restrict__ wcur, int* __restrict__ bsums,
        float* __restrict__ bnacc, int2* __restrict__ esort) {
    cg::grid_group grid = cg::this_grid();
    __shared__ int sd[256];
    int t = threadIdx.x;
    int gtid = blockIdx.x * 256 + t;

    // ---- P0: zero cnt/bnacc | weight prep | x -> bf16 ----
    for (int i = gtid; i < N_NODES; i += GSZ) cnt[i] = 0;
    if (gtid < 256) bnacc[gtid] = 0.f;
    for (int j = gtid; j < 9216; j += GSZ) {
        const float* W; short* hi; short* lo; int ct, tt;
        if (j < 8192) {
            int m = j >> 11;
            W  = (m == 0) ? Wl0 : (m == 1) ? Wr0 : (m == 2) ? Wl1 : Wr1;
            hi = (m == 0) ? fWl0h : (m == 1) ? fWr0h : (m == 2) ? fWl1h : fWr1h;
            lo = (m == 0) ? fWl0l : (m == 1) ? fWr0l : (m == 2) ? fWl1l : fWr1l;
            ct = (j >> 8) & 7; tt = j & 255;
        } else {
            W = Wp; hi = fWph; lo = fWpl;
            ct = (j - 8192) >> 8; tt = (j - 8192) & 255;
        }
        int lane = tt & 63, ks = (tt >> 6) & 3;
        int row = ct * 16 + (lane & 15);
        int k0 = ks * 32 + ((lane >> 4) << 3);
        float4 v0 = *reinterpret_cast<const float4*>(&W[(size_t)row * DIM + k0]);
        float4 v1 = *reinterpret_cast<const float4*>(&W[(size_t)row * DIM + k0 + 4]);
        s16x8 h8, l8;
        f2hl8(v0, v1, h8, l8);
        int fi = ct * 256 + ks * 64 + lane;
        *reinterpret_cast<s16x8*>(&hi[(size_t)fi * 8]) = h8;
        *reinterpret_cast<s16x8*>(&lo[(size_t)fi * 8]) = l8;
    }
    for (int i = gtid; i < N_NODES * DIM / 8; i += GSZ) {
        float4 a = reinterpret_cast<const float4*>(x)[(size_t)i * 2];
        float4 c = reinterpret_cast<const float4*>(x)[(size_t)i * 2 + 1];
        ushort4 oa, ob;
        oa.x = f2b(a.x); oa.y = f2b(a.y); oa.z = f2b(a.z); oa.w = f2b(a.w);
        ob.x = f2b(c.x); ob.y = f2b(c.y); ob.z = f2b(c.z); ob.w = f2b(c.w);
        reinterpret_cast<ushort4*>(x_bf)[(size_t)i * 2] = oa;
        reinterpret_cast<ushort4*>(x_bf)[(size_t)i * 2 + 1] = ob;
    }
    grid.sync();

    // ---- P1: degree histogram ----
    for (int e = gtid; e < N_EDGES; e += GSZ) atomicAdd(&cnt[dst[e]], 1);
    grid.sync();

    // ---- P2: per-chunk (1024) exclusive scan ----
    if (blockIdx.x < 98) {
        int base = blockIdx.x * 1024;
        int v[4]; int tsum = 0;
#pragma unroll
        for (int i = 0; i < 4; ++i) {
            int idx = base + t * 4 + i;
            v[i] = (idx < N_NODES) ? cnt[idx] : 0;
            tsum += v[i];
        }
        sd[t] = tsum;
        __syncthreads();
        for (int off2 = 1; off2 < 256; off2 <<= 1) {
            int u = (t >= off2) ? sd[t - off2] : 0;
            __syncthreads();
            sd[t] += u;
            __syncthreads();
        }
        int run = sd[t] - tsum;
#pragma unroll
        for (int i = 0; i < 4; ++i) {
            int idx = base + t * 4 + i;
            if (idx < N_NODES) rowptr[idx] = run;
            run += v[i];
        }
        if (t == 255) bsums[blockIdx.x] = sd[255];
    }
    grid.sync();

    // ---- P3: scan the 98 block sums (block 0) ----
    if (blockIdx.x == 0) {
        int v = (t < 98) ? bsums[t] : 0;
        sd[t] = v;
        __syncthreads();
        for (int off2 = 1; off2 < 256; off2 <<= 1) {
            int u = (t >= off2) ? sd[t - off2] : 0;
            __syncthreads();
            sd[t] += u;
            __syncthreads();
        }
        if (t < 98) bsums[t] = sd[t] - v;
    }
    grid.sync();

    // ---- P4: add chunk offsets, init wcur ----
    for (int i = gtid; i < N_NODES; i += GSZ) {
        int val = rowptr[i] + bsums[i >> 10];
        rowptr[i] = val;
        wcur[i] = val;
    }
    if (gtid == 0) rowptr[N_NODES] = N_EDGES;
    grid.sync();

    // ---- P5: bucket edges by dst ----
    for (int e = gtid; e < N_EDGES; e += GSZ) {
        int d = dst[e];
        int p = atomicAdd(&wcur[d], 1);
        esort[p] = make_int2(e, src[e]);
    }
}

// ---------------- gather-aggregate: one wave/node, 4 edges/half-wave --------
// MODE 0: read f32 xe random, WRITE xe_s bf16 sequential, no BN.  AGG out bf16.
// MODE 1: read xe_s bf16 sequential, BN+relu on gathered F (BN from bnacc).
// MODE 2: fallback, read f32 xe random, BN+relu on gathered F.
template <int MODE>
__global__ __launch_bounds__(256) void k_agg(
        const unsigned short* __restrict__ Fb, const float* __restrict__ xe,
        unsigned short* __restrict__ xe_s,
        const int* __restrict__ rowptr, const int2* __restrict__ esort,
        unsigned short* __restrict__ agg, const float* __restrict__ bnacc,
        const float* __restrict__ gamma, const float* __restrict__ beta) {
    int wid = (blockIdx.x * 256 + threadIdx.x) >> 6;
    int lane = threadIdx.x & 63;
    if (wid >= N_NODES) return;
    int half = lane >> 5;
    int l = lane & 31;
    int p0 = rowptr[wid], p1 = rowptr[wid + 1];
    if (p0 == p1) {
        if (half == 0) {
            ushort4 z = make_ushort4(0, 0, 0, 0);
            *reinterpret_cast<ushort4*>(&agg[(size_t)wid * DIM + l * 4]) = z;
        }
        return;
    }
    float scv[4], shv[4];
    if (MODE != 0) {
#pragma unroll
        for (int i = 0; i < 4; ++i) {
            int d = l * 4 + i;
            float mu = bnacc[d] * (1.f / N_NODES);
            float var = bnacc[128 + d] * (1.f / N_NODES) - mu * mu;
            float rstd = rsqrtf(var + BN_EPS);
            scv[i] = gamma[d] * rstd;
            shv[i] = beta[d] - mu * scv[i];
        }
    }
    float4 acc = make_float4(0.f, 0.f, 0.f, 0.f);
    for (int p = p0; p < p1; p += 8) {
#pragma unroll
        for (int j = 0; j < 4; ++j) {
            int q = p + j * 2 + half;
            int qc = min(q, p1 - 1);
            int2 es = esort[qc];
            float4 a = bexp4(*reinterpret_cast<const ushort4*>(
                &Fb[(size_t)es.y * DIM + l * 4]));
            float4 b;
            if (MODE == 1) {
                b = bexp4(*reinterpret_cast<const ushort4*>(
                    &xe_s[(size_t)qc * DIM + l * 4]));
            } else {
                b = *reinterpret_cast<const float4*>(
                    &xe[(size_t)es.x * DIM + l * 4]);
            }
            if (MODE != 0) {
                a.x = fmaxf(a.x * scv[0] + shv[0], 0.f);
                a.y = fmaxf(a.y * scv[1] + shv[1], 0.f);
                a.z = fmaxf(a.z * scv[2] + shv[2], 0.f);
                a.w = fmaxf(a.w * scv[3] + shv[3], 0.f);
            }
            if (q < p1) {
                if (MODE == 0) {
                    ushort4 o;
                    o.x = f2b(b.x); o.y = f2b(b.y);
                    o.z = f2b(b.z); o.w = f2b(b.w);
                    *reinterpret_cast<ushort4*>(&xe_s[(size_t)qc * DIM + l * 4]) = o;
                }
                acc.x += fmaxf(a.x + b.x, 0.f);
                acc.y += fmaxf(a.y + b.y, 0.f);
                acc.z += fmaxf(a.z + b.z, 0.f);
                acc.w += fmaxf(a.w + b.w, 0.f);
            }
        }
    }
    acc.x += __shfl_xor(acc.x, 32);
    acc.y += __shfl_xor(acc.y, 32);
    acc.z += __shfl_xor(acc.z, 32);
    acc.w += __shfl_xor(acc.w, 32);
    if (half == 0) {
        float s = 1.f / (float)(p1 - p0);
        ushort4 o;
        o.x = f2b(acc.x * s); o.y = f2b(acc.y * s);
        o.z = f2b(acc.z * s); o.w = f2b(acc.w * s);
        *reinterpret_cast<ushort4*>(&agg[(size_t)wid * DIM + l * 4]) = o;
    }
}

// ---------------- MFMA dual GEMM: OUT = Abf@W1^T + bn?(Bbf)@W2^T + bias ------
__global__ __launch_bounds__(256) void k_gemm2(
        const unsigned short* __restrict__ Abf, const unsigned short* __restrict__ Bbf,
        const short* __restrict__ fW1h, const short* __restrict__ fW1l,
        const short* __restrict__ fW2h, const short* __restrict__ fW2l,
        const float* __restrict__ bias, unsigned short* __restrict__ OUTb,
        float* __restrict__ bnacc, const float* __restrict__ gamma,
        const float* __restrict__ beta, int doBN, int bnB) {
    __shared__ float bnsc_s[256];
    int t = threadIdx.x, w = t >> 6, l = t & 63;
    if (bnB) {
        if (t < 128) {
            float mu = bnacc[t] * (1.f / N_NODES);
            float var = bnacc[128 + t] * (1.f / N_NODES) - mu * mu;
            float rstd = rsqrtf(var + BN_EPS);
            float sc = gamma[t] * rstd;
            bnsc_s[t] = sc;
            bnsc_s[128 + t] = beta[t] - mu * sc;
        }
        __syncthreads();
    }
    int n0 = blockIdx.x * 128;
    int r = l & 15, kh = l >> 4;
    int row0 = n0 + w * 16 + r;
    int row1 = row0 + 64;
    int n_0 = min(row0, N_NODES - 1);
    int n_1 = min(row1, N_NODES - 1);

    f32x4 acc0[8], acc1[8];
#pragma unroll
    for (int ct = 0; ct < 8; ++ct) {
        acc0[ct] = (f32x4){0.f, 0.f, 0.f, 0.f};
        acc1[ct] = (f32x4){0.f, 0.f, 0.f, 0.f};
    }
    const s16x8* w1h = (const s16x8*)fW1h;
    const s16x8* w1l = (const s16x8*)fW1l;
    const s16x8* w2h = (const s16x8*)fW2h;
    const s16x8* w2l = (const s16x8*)fW2l;

#pragma unroll
    for (int ks = 0; ks < 4; ++ks) {
        int kb = ks * 32 + kh * 8;
        s16x8 a0 = *reinterpret_cast<const s16x8*>(&Abf[(size_t)n_0 * DIM + kb]);
        s16x8 a1 = *reinterpret_cast<const s16x8*>(&Abf[(size_t)n_1 * DIM + kb]);
        s16x8 b0 = *reinterpret_cast<const s16x8*>(&Bbf[(size_t)n_0 * DIM + kb]);
        s16x8 b1 = *reinterpret_cast<const s16x8*>(&Bbf[(size_t)n_1 * DIM + kb]);
        if (bnB) {
#pragma unroll
            for (int i = 0; i < 8; ++i) {
                int d = kb + i;
                float v = b2f((unsigned short)b0[i]);
                b0[i] = (short)f2b(fmaxf(v * bnsc_s[d] + bnsc_s[128 + d], 0.f));
                v = b2f((unsigned short)b1[i]);
                b1[i] = (short)f2b(fmaxf(v * bnsc_s[d] + bnsc_s[128 + d], 0.f));
            }
        }
        int fb = ks * 64 + l;
#pragma unroll
        for (int ct = 0; ct < 8; ++ct) {
            int fi = ct * 256 + fb;
            s16x8 wh1 = w1h[fi], wl1 = w1l[fi];
            s16x8 wh2 = w2h[fi], wl2 = w2l[fi];
            acc0[ct] = MFMA_BF16(a0, wh1, acc0[ct], 0, 0, 0);
            acc0[ct] = MFMA_BF16(a0, wl1, acc0[ct], 0, 0, 0);
            acc0[ct] = MFMA_BF16(b0, wh2, acc0[ct], 0, 0, 0);
            acc0[ct] = MFMA_BF16(b0, wl2, acc0[ct], 0, 0, 0);
            acc1[ct] = MFMA_BF16(a1, wh1, acc1[ct], 0, 0, 0);
            acc1[ct] = MFMA_BF16(a1, wl1, acc1[ct], 0, 0, 0);
            acc1[ct] = MFMA_BF16(b1, wh2, acc1[ct], 0, 0, 0);
            acc1[ct] = MFMA_BF16(b1, wl2, acc1[ct], 0, 0, 0);
        }
    }

    float p1s[8], p2s[8];
    int col0 = l & 15;
    int nb0 = n0 + w * 16 + (kh << 2);
    int nb1 = nb0 + 64;
#pragma unroll
    for (int ct = 0; ct < 8; ++ct) {
        float bj = bias[ct * 16 + col0];
        float s1 = 0.f, s2 = 0.f;
#pragma unroll
        for (int rr = 0; rr < 4; ++rr) {
            int n = nb0 + rr;
            float h = acc0[ct][rr] + bj;
            if (n < N_NODES) {
                OUTb[(size_t)n * DIM + ct * 16 + col0] = f2b(h);
                s1 += h; s2 += h * h;
            }
            n = nb1 + rr;
            h = acc1[ct][rr] + bj;
            if (n < N_NODES) {
                OUTb[(size_t)n * DIM + ct * 16 + col0] = f2b(h);
                s1 += h; s2 += h * h;
            }
        }
        p1s[ct] = s1; p2s[ct] = s2;
    }
    if (doBN) {
        __shared__ float red1[512];
        __shared__ float red2[512];
#pragma unroll
        for (int ct = 0; ct < 8; ++ct) {
            p1s[ct] += __shfl_xor(p1s[ct], 16);
            p1s[ct] += __shfl_xor(p1s[ct], 32);
            p2s[ct] += __shfl_xor(p2s[ct], 16);
            p2s[ct] += __shfl_xor(p2s[ct], 32);
        }
        if (l < 16) {
#pragma unroll
            for (int ct = 0; ct < 8; ++ct) {
                red1[w * 128 + ct * 16 + l] = p1s[ct];
                red2[w * 128 + ct * 16 + l] = p2s[ct];
            }
        }
        __syncthreads();
        if (t < 128) {
            float s1 = red1[t] + red1[128 + t] + red1[256 + t] + red1[384 + t];
            float s2 = red2[t] + red2[128 + t] + red2[256 + t] + red2[384 + t];
            atomicAdd(&bnacc[t], s1);
            atomicAdd(&bnacc[128 + t], s2);
        }
    }
}

// ---------------- fused pool (blocks 0..127) + projection (blocks 128..) ----
__global__ __launch_bounds__(256) void k_poolproj(
        const unsigned short* __restrict__ H1b, const int* __restrict__ batch,
        float* __restrict__ gout, const short* __restrict__ fWph,
        const short* __restrict__ fWpl, const float* __restrict__ bp,
        float* __restrict__ OUT) {
    int t = threadIdx.x;
    if (blockIdx.x < NG) {
        __shared__ float red[2][128];
        int g = blockIdx.x;
        int d = t & 127;
        int sl = t >> 7;
        int lo = 0, hi = N_NODES;
        while (lo < hi) { int m = (lo + hi) >> 1; if (batch[m] < g) lo = m + 1; else hi = m; }
        int s = lo;
        lo = 0; hi = N_NODES;
        while (lo < hi) { int m = (lo + hi) >> 1; if (batch[m] < g + 1) lo = m + 1; else hi = m; }
        int e = lo;
        float sum = 0.f;
        for (int n = s + sl; n < e; n += 2) sum += b2f(H1b[(size_t)n * DIM + d]);
        red[sl][d] = sum;
        __syncthreads();
        if (t < 128)
            gout[g * DIM + d] = (red[0][d] + red[1][d]) / (float)max(e - s, 1);
        return;
    }
    int w = t >> 6, l = t & 63;
    int n0 = (blockIdx.x - NG) * 128;
    int r = l & 15, kh = l >> 4;
    int row0 = n0 + w * 16 + r;
    int row1 = row0 + 64;
    int n_0 = min(row0, N_NODES - 1);
    int n_1 = min(row1, N_NODES - 1);
    f32x4 acc0[4], acc1[4];
#pragma unroll
    for (int ct = 0; ct < 4; ++ct) {
        acc0[ct] = (f32x4){0.f, 0.f, 0.f, 0.f};
        acc1[ct] = (f32x4){0.f, 0.f, 0.f, 0.f};
    }
    const s16x8* wph = (const s16x8*)fWph;
    const s16x8* wpl = (const s16x8*)fWpl;
#pragma unroll
    for (int ks = 0; ks < 4; ++ks) {
        int kb = ks * 32 + kh * 8;
        s16x8 r0 = *reinterpret_cast<const s16x8*>(&H1b[(size_t)n_0 * DIM + kb]);
        s16x8 r1 = *reinterpret_cast<const s16x8*>(&H1b[(size_t)n_1 * DIM + kb]);
        s16x8 a0, a1;
#pragma unroll
        for (int i = 0; i < 8; ++i) {
            a0[i] = r0[i] < 0 ? (short)0 : r0[i];
            a1[i] = r1[i] < 0 ? (short)0 : r1[i];
        }
        int fb = ks * 64 + l;
#pragma unroll
        for (int ct = 0; ct < 4; ++ct) {
            int fi = ct * 256 + fb;
            s16x8 wh = wph[fi], wl = wpl[fi];
            acc0[ct] = MFMA_BF16(a0, wh, acc0[ct], 0, 0, 0);
            acc0[ct] = MFMA_BF16(a0, wl, acc0[ct], 0, 0, 0);
            acc1[ct] = MFMA_BF16(a1, wh, acc1[ct], 0, 0, 0);
            acc1[ct] = MFMA_BF16(a1, wl, acc1[ct], 0, 0, 0);
        }
    }
    int col0 = l & 15;
    int nb0 = n0 + w * 16 + (kh << 2);
    int nb1 = nb0 + 64;
#pragma unroll
    for (int ct = 0; ct < 4; ++ct) {
        float bj = bp[ct * 16 + col0];
#pragma unroll
        for (int rr = 0; rr < 4; ++rr) {
            int n = nb0 + rr;
            if (n < N_NODES)
                OUT[(size_t)n * NCLS + ct * 16 + col0] = acc0[ct][rr] + bj;
            n = nb1 + rr;
            if (n < N_NODES)
                OUT[(size_t)n * NCLS + ct * 16 + col0] = acc1[ct][rr] + bj;
        }
    }
}

extern "C" void kernel_launch(void* const* d_in, const int* in_sizes, int n_in,
                              void* d_out, int out_size, void* d_ws, size_t ws_size,
                              hipStream_t stream) {
    (void)in_sizes; (void)n_in; (void)out_size;
    const float* x     = (const float*)d_in[0];
    const float* xe    = (const float*)d_in[1];
    const int*   eidx  = (const int*)d_in[2];
    const int*   batch = (const int*)d_in[3];
    const float* Wl0   = (const float*)d_in[4];
    const float* bl0   = (const float*)d_in[5];
    const float* Wr0   = (const float*)d_in[6];
    const float* Wl1   = (const float*)d_in[7];
    const float* bl1   = (const float*)d_in[8];
    const float* Wr1   = (const float*)d_in[9];
    const float* gamma0 = (const float*)d_in[10];
    const float* beta0  = (const float*)d_in[11];
    const float* Wp    = (const float*)d_in[12];
    const float* bp    = (const float*)d_in[13];
    const int* srcp = eidx;
    const int* dstp = eidx + N_EDGES;

    char* ws = (char*)d_ws;
    size_t off = 0;
    auto carve = [&](size_t bytes) {
        void* p = ws + off;
        off = (off + bytes + 255) & ~(size_t)255;
        return p;
    };
    int*   cnt    = (int*)carve((size_t)N_NODES * 4);
    int*   rowptr = (int*)carve((size_t)(N_NODES + 1) * 4);
    int*   wcur   = (int*)carve((size_t)N_NODES * 4);
    int*   bsums  = (int*)carve(128 * 4);
    float* bnacc  = (float*)carve(256 * 4);
    int2*  esort  = (int2*)carve((size_t)N_EDGES * 8);
    unsigned short* AGGb = (unsigned short*)carve((size_t)N_NODES * DIM * 2);
    unsigned short* x_bf = (unsigned short*)carve((size_t)N_NODES * DIM * 2);
    unsigned short* H_bf = (unsigned short*)carve((size_t)N_NODES * DIM * 2);
    unsigned short* H1b  = (unsigned short*)carve((size_t)N_NODES * DIM * 2);
    short* fWl0h = (short*)carve(16384 * 2);
    short* fWl0l = (short*)carve(16384 * 2);
    short* fWr0h = (short*)carve(16384 * 2);
    short* fWr0l = (short*)carve(16384 * 2);
    short* fWl1h = (short*)carve(16384 * 2);
    short* fWl1l = (short*)carve(16384 * 2);
    short* fWr1h = (short*)carve(16384 * 2);
    short* fWr1l = (short*)carve(16384 * 2);
    short* fWph  = (short*)carve(8192 * 2);
    short* fWpl  = (short*)carve(8192 * 2);

    size_t xes_bytes = (size_t)N_EDGES * DIM * 2;   // 409.6 MB
    int seq = (off + xes_bytes + 256 <= ws_size) ? 1 : 0;
    unsigned short* xe_s = seq ? (unsigned short*)carve(xes_bytes) : nullptr;

    float* out_h = (float*)d_out;
    float* out_g = out_h + (size_t)N_NODES * NCLS;

    // ---- single cooperative prologue ----
    void* args[] = {
        (void*)&Wl0, (void*)&Wr0, (void*)&Wl1, (void*)&Wr1, (void*)&Wp,
        (void*)&fWl0h, (void*)&fWl0l, (void*)&fWr0h, (void*)&fWr0l,
        (void*)&fWl1h, (void*)&fWl1l, (void*)&fWr1h, (void*)&fWr1l,
        (void*)&fWph, (void*)&fWpl,
        (void*)&x, (void*)&x_bf, (void*)&srcp, (void*)&dstp,
        (void*)&cnt, (void*)&rowptr, (void*)&wcur, (void*)&bsums,
        (void*)&bnacc, (void*)&esort
    };
    hipLaunchCooperativeKernel((const void*)k_coop, dim3(COOP_BLOCKS), dim3(256),
                               args, 0, stream);

    int ablocks = (N_NODES * 64 + 255) / 256;   // 25000
    int gblocks = (N_NODES + 127) / 128;        // 782

    // layer 0
    if (seq)
        k_agg<0><<<ablocks, 256, 0, stream>>>(x_bf, xe, xe_s, rowptr, esort, AGGb,
                                              nullptr, nullptr, nullptr);
    else
        k_agg<2><<<ablocks, 256, 0, stream>>>(x_bf, xe, nullptr, rowptr, esort, AGGb,
                                              bnacc, gamma0, beta0);
    k_gemm2<<<gblocks, 256, 0, stream>>>(AGGb, x_bf, fWl0h, fWl0l, fWr0h, fWr0l,
                                         bl0, H_bf, bnacc, gamma0, beta0, 1, 0);

    // layer 1 (BN folded into consumers, computed from bnacc)
    if (seq)
        k_agg<1><<<ablocks, 256, 0, stream>>>(H_bf, xe, xe_s, rowptr, esort, AGGb,
                                              bnacc, gamma0, beta0);
    else
        k_agg<2><<<ablocks, 256, 0, stream>>>(H_bf, xe, nullptr, rowptr, esort, AGGb,
                                              bnacc, gamma0, beta0);
    k_gemm2<<<gblocks, 256, 0, stream>>>(AGGb, H_bf, fWl1h, fWl1l, fWr1h, fWr1l,
                                         bl1, H1b, bnacc, gamma0, beta0, 0, 1);

    // readout: pool + proj in one launch
    k_poolproj<<<NG + gblocks, 256, 0, stream>>>(H1b, batch, out_g,
                                                 fWph, fWpl, bp, out_h);
}

// Round 11
// 853.756 us; speedup vs baseline: 1.4105x; 1.4105x over previous
//
#include <hip/hip_runtime.h>

#define N_NODES 100000
#define N_EDGES 1600000
#define DIM 128
#define NCLS 64
#define NG 128
#define BN_EPS 1e-5f

typedef __attribute__((ext_vector_type(8))) short s16x8;
typedef __attribute__((ext_vector_type(4))) float f32x4;
#define MFMA_BF16 __builtin_amdgcn_mfma_f32_16x16x32_bf16

// f32 -> bf16 RNE
__device__ __forceinline__ unsigned short f2b(float x) {
    unsigned u = __float_as_uint(x);
    return (unsigned short)((u + 0x7FFFu + ((u >> 16) & 1u)) >> 16);
}
__device__ __forceinline__ float b2f(unsigned short s) {
    return __uint_as_float(((unsigned)s) << 16);
}
__device__ __forceinline__ float4 bexp4(ushort4 u) {
    float4 f;
    f.x = b2f(u.x); f.y = b2f(u.y); f.z = b2f(u.z); f.w = b2f(u.w);
    return f;
}

// split 8 f32 into bf16 hi + bf16 lo (truncation)
__device__ __forceinline__ void f2hl8(float4 v0, float4 v1, s16x8& h8, s16x8& l8) {
    float vv[8] = {v0.x, v0.y, v0.z, v0.w, v1.x, v1.y, v1.z, v1.w};
#pragma unroll
    for (int i = 0; i < 8; ++i) {
        unsigned u = __float_as_uint(vv[i]);
        short h = (short)(u >> 16);
        float r = vv[i] - __uint_as_float(u & 0xFFFF0000u);
        short l = (short)(__float_as_uint(r) >> 16);
        h8[i] = h;
        l8[i] = l;
    }
}

// ---------------- mega kernel 0: wprep(36) | cvt x->x_bf(6250) | hist(6250) ----
// also zeroes bnacc (block 0, free)
__global__ __launch_bounds__(256) void k_mega0(
        const float* __restrict__ Wl0, const float* __restrict__ Wr0,
        const float* __restrict__ Wl1, const float* __restrict__ Wr1,
        const float* __restrict__ Wp,
        short* __restrict__ fWl0h, short* __restrict__ fWl0l,
        short* __restrict__ fWr0h, short* __restrict__ fWr0l,
        short* __restrict__ fWl1h, short* __restrict__ fWl1l,
        short* __restrict__ fWr1h, short* __restrict__ fWr1l,
        short* __restrict__ fWph, short* __restrict__ fWpl,
        const float* __restrict__ x, unsigned short* __restrict__ x_bf,
        const int* __restrict__ dst, int* __restrict__ cnt,
        float* __restrict__ bnacc) {
    int b = blockIdx.x;
    if (b == 0) bnacc[threadIdx.x] = 0.f;  // 256 threads cover bnacc[256]
    if (b < 36) {
        const float* W; short* hi; short* lo; int ct;
        if (b < 8)       { W = Wl0; hi = fWl0h; lo = fWl0l; ct = b; }
        else if (b < 16) { W = Wr0; hi = fWr0h; lo = fWr0l; ct = b - 8; }
        else if (b < 24) { W = Wl1; hi = fWl1h; lo = fWl1l; ct = b - 16; }
        else if (b < 32) { W = Wr1; hi = fWr1h; lo = fWr1l; ct = b - 24; }
        else             { W = Wp;  hi = fWph;  lo = fWpl;  ct = b - 32; }
        if (b >= 32 && ct >= 4) return;
        int tt = threadIdx.x;
        int lane = tt & 63, ks = (tt >> 6) & 3;
        int row = ct * 16 + (lane & 15);
        int k0 = ks * 32 + ((lane >> 4) << 3);
        float4 v0 = *reinterpret_cast<const float4*>(&W[(size_t)row * DIM + k0]);
        float4 v1 = *reinterpret_cast<const float4*>(&W[(size_t)row * DIM + k0 + 4]);
        s16x8 h8, l8;
        f2hl8(v0, v1, h8, l8);
        int t = ct * 256 + ks * 64 + lane;
        *reinterpret_cast<s16x8*>(&hi[(size_t)t * 8]) = h8;
        *reinterpret_cast<s16x8*>(&lo[(size_t)t * 8]) = l8;
    } else if (b < 36 + 6250) {
        int i = (b - 36) * 256 + threadIdx.x;   // float8 index, exactly 1.6M
        float4 a = reinterpret_cast<const float4*>(x)[(size_t)i * 2];
        float4 c = reinterpret_cast<const float4*>(x)[(size_t)i * 2 + 1];
        ushort4 oa, ob;
        oa.x = f2b(a.x); oa.y = f2b(a.y); oa.z = f2b(a.z); oa.w = f2b(a.w);
        ob.x = f2b(c.x); ob.y = f2b(c.y); ob.z = f2b(c.z); ob.w = f2b(c.w);
        reinterpret_cast<ushort4*>(x_bf)[(size_t)i * 2] = oa;
        reinterpret_cast<ushort4*>(x_bf)[(size_t)i * 2 + 1] = ob;
    } else {
        int e = (b - 36 - 6250) * 256 + threadIdx.x;  // exactly 1.6M
        atomicAdd(&cnt[dst[e]], 1);
    }
}

// ---------------- exclusive scan (3 kernels) ----------------
__global__ void k_scan1(const int* __restrict__ cnt, int* __restrict__ rowptr,
                        int* __restrict__ bsums) {
    __shared__ int sd[1024];
    int tid = threadIdx.x;
    int i = blockIdx.x * 1024 + tid;
    int v = (i < N_NODES) ? cnt[i] : 0;
    sd[tid] = v;
    __syncthreads();
    for (int off = 1; off < 1024; off <<= 1) {
        int t2 = (tid >= off) ? sd[tid - off] : 0;
        __syncthreads();
        sd[tid] += t2;
        __syncthreads();
    }
    if (i < N_NODES) rowptr[i] = sd[tid] - v;
    if (tid == 1023) bsums[blockIdx.x] = sd[tid];
}

__global__ void k_scan2(int* __restrict__ bsums, int nb) {
    __shared__ int sd[128];
    int t = threadIdx.x;
    int v = (t < nb) ? bsums[t] : 0;
    sd[t] = v;
    __syncthreads();
    for (int off = 1; off < 128; off <<= 1) {
        int u = (t >= off) ? sd[t - off] : 0;
        __syncthreads();
        sd[t] += u;
        __syncthreads();
    }
    if (t < nb) bsums[t] = sd[t] - v;
}

__global__ void k_scan3(int* __restrict__ rowptr, const int* __restrict__ bsums,
                        int* __restrict__ wcur) {
    int i = blockIdx.x * 1024 + threadIdx.x;
    if (i < N_NODES) {
        int v = rowptr[i] + bsums[blockIdx.x];
        rowptr[i] = v;
        wcur[i] = v;
    }
    if (i == N_NODES - 1) rowptr[N_NODES] = N_EDGES;
}

// ---------------- bucket edges by dst ----------------
__global__ void k_scatter(const int* __restrict__ src, const int* __restrict__ dst,
                          int* __restrict__ wcur, int2* __restrict__ esort) {
    int e = blockIdx.x * 256 + threadIdx.x;
    if (e < N_EDGES) {
        int d = dst[e];
        int p = atomicAdd(&wcur[d], 1);
        esort[p] = make_int2(e, src[e]);
    }
}

// ---------------- gather-aggregate: one wave/node ----------------
// esort hoisted: lanes 0..7 vector-load the trip's 8 entries, __shfl distributes;
// next trip's esort load is software-pipelined over current row loads.
// MODE 0: read f32 xe random, WRITE xe_s bf16 sequential, no BN.  AGG out bf16.
// MODE 1: read xe_s bf16 sequential, BN+relu on gathered F (BN from bnacc).
// MODE 2: fallback, read f32 xe random, BN+relu on gathered F.
template <int MODE>
__global__ __launch_bounds__(256) void k_agg(
        const unsigned short* __restrict__ Fb, const float* __restrict__ xe,
        unsigned short* __restrict__ xe_s,
        const int* __restrict__ rowptr, const int2* __restrict__ esort,
        unsigned short* __restrict__ agg, const float* __restrict__ bnacc,
        const float* __restrict__ gamma, const float* __restrict__ beta) {
    int wid = (blockIdx.x * 256 + threadIdx.x) >> 6;
    int lane = threadIdx.x & 63;
    if (wid >= N_NODES) return;
    int half = lane >> 5;
    int l = lane & 31;
    int p0 = rowptr[wid], p1 = rowptr[wid + 1];
    if (p0 == p1) {
        if (half == 0) {
            ushort4 z = make_ushort4(0, 0, 0, 0);
            *reinterpret_cast<ushort4*>(&agg[(size_t)wid * DIM + l * 4]) = z;
        }
        return;
    }
    float scv[4], shv[4];
    if (MODE != 0) {
#pragma unroll
        for (int i = 0; i < 4; ++i) {
            int d = l * 4 + i;
            float mu = bnacc[d] * (1.f / N_NODES);
            float var = bnacc[128 + d] * (1.f / N_NODES) - mu * mu;
            float rstd = rsqrtf(var + BN_EPS);
            scv[i] = gamma[d] * rstd;
            shv[i] = beta[d] - mu * scv[i];
        }
    }
    float4 acc = make_float4(0.f, 0.f, 0.f, 0.f);
    int2 ev = esort[min(p0 + (lane & 7), p1 - 1)];
    for (int p = p0; p < p1; p += 8) {
        int pn = p + 8;
        int2 evn;
        if (pn < p1) evn = esort[min(pn + (lane & 7), p1 - 1)];
#pragma unroll
        for (int j = 0; j < 4; ++j) {
            int k = j * 2 + half;     // entry index within trip, 0..7
            int q = p + k;
            int esx = __shfl(ev.x, k);
            int esy = __shfl(ev.y, k);
            float4 a = bexp4(*reinterpret_cast<const ushort4*>(
                &Fb[(size_t)esy * DIM + l * 4]));
            float4 b;
            if (MODE == 1) {
                int qc = min(q, p1 - 1);
                b = bexp4(*reinterpret_cast<const ushort4*>(
                    &xe_s[(size_t)qc * DIM + l * 4]));
            } else {
                b = *reinterpret_cast<const float4*>(
                    &xe[(size_t)esx * DIM + l * 4]);
            }
            if (MODE != 0) {
                a.x = fmaxf(a.x * scv[0] + shv[0], 0.f);
                a.y = fmaxf(a.y * scv[1] + shv[1], 0.f);
                a.z = fmaxf(a.z * scv[2] + shv[2], 0.f);
                a.w = fmaxf(a.w * scv[3] + shv[3], 0.f);
            }
            if (q < p1) {
                if (MODE == 0) {
                    ushort4 o;
                    o.x = f2b(b.x); o.y = f2b(b.y);
                    o.z = f2b(b.z); o.w = f2b(b.w);
                    *reinterpret_cast<ushort4*>(&xe_s[(size_t)q * DIM + l * 4]) = o;
                }
                acc.x += fmaxf(a.x + b.x, 0.f);
                acc.y += fmaxf(a.y + b.y, 0.f);
                acc.z += fmaxf(a.z + b.z, 0.f);
                acc.w += fmaxf(a.w + b.w, 0.f);
            }
        }
        if (pn < p1) ev = evn;
    }
    acc.x += __shfl_xor(acc.x, 32);
    acc.y += __shfl_xor(acc.y, 32);
    acc.z += __shfl_xor(acc.z, 32);
    acc.w += __shfl_xor(acc.w, 32);
    if (half == 0) {
        float s = 1.f / (float)(p1 - p0);
        ushort4 o;
        o.x = f2b(acc.x * s); o.y = f2b(acc.y * s);
        o.z = f2b(acc.z * s); o.w = f2b(acc.w * s);
        *reinterpret_cast<ushort4*>(&agg[(size_t)wid * DIM + l * 4]) = o;
    }
}

// ---------------- MFMA dual GEMM: OUT = Abf@W1^T + bn?(Bbf)@W2^T + bias ------
__global__ __launch_bounds__(256) void k_gemm2(
        const unsigned short* __restrict__ Abf, const unsigned short* __restrict__ Bbf,
        const short* __restrict__ fW1h, const short* __restrict__ fW1l,
        const short* __restrict__ fW2h, const short* __restrict__ fW2l,
        const float* __restrict__ bias, unsigned short* __restrict__ OUTb,
        float* __restrict__ bnacc, const float* __restrict__ gamma,
        const float* __restrict__ beta, int doBN, int bnB) {
    __shared__ float bnsc_s[256];
    int t = threadIdx.x, w = t >> 6, l = t & 63;
    if (bnB) {
        if (t < 128) {
            float mu = bnacc[t] * (1.f / N_NODES);
            float var = bnacc[128 + t] * (1.f / N_NODES) - mu * mu;
            float rstd = rsqrtf(var + BN_EPS);
            float sc = gamma[t] * rstd;
            bnsc_s[t] = sc;
            bnsc_s[128 + t] = beta[t] - mu * sc;
        }
        __syncthreads();
    }
    int n0 = blockIdx.x * 128;
    int r = l & 15, kh = l >> 4;
    int row0 = n0 + w * 16 + r;
    int row1 = row0 + 64;
    int n_0 = min(row0, N_NODES - 1);
    int n_1 = min(row1, N_NODES - 1);

    f32x4 acc0[8], acc1[8];
#pragma unroll
    for (int ct = 0; ct < 8; ++ct) {
        acc0[ct] = (f32x4){0.f, 0.f, 0.f, 0.f};
        acc1[ct] = (f32x4){0.f, 0.f, 0.f, 0.f};
    }
    const s16x8* w1h = (const s16x8*)fW1h;
    const s16x8* w1l = (const s16x8*)fW1l;
    const s16x8* w2h = (const s16x8*)fW2h;
    const s16x8* w2l = (const s16x8*)fW2l;

#pragma unroll
    for (int ks = 0; ks < 4; ++ks) {
        int kb = ks * 32 + kh * 8;
        s16x8 a0 = *reinterpret_cast<const s16x8*>(&Abf[(size_t)n_0 * DIM + kb]);
        s16x8 a1 = *reinterpret_cast<const s16x8*>(&Abf[(size_t)n_1 * DIM + kb]);
        s16x8 b0 = *reinterpret_cast<const s16x8*>(&Bbf[(size_t)n_0 * DIM + kb]);
        s16x8 b1 = *reinterpret_cast<const s16x8*>(&Bbf[(size_t)n_1 * DIM + kb]);
        if (bnB) {
#pragma unroll
            for (int i = 0; i < 8; ++i) {
                int d = kb + i;
                float v = b2f((unsigned short)b0[i]);
                b0[i] = (short)f2b(fmaxf(v * bnsc_s[d] + bnsc_s[128 + d], 0.f));
                v = b2f((unsigned short)b1[i]);
                b1[i] = (short)f2b(fmaxf(v * bnsc_s[d] + bnsc_s[128 + d], 0.f));
            }
        }
        int fb = ks * 64 + l;
#pragma unroll
        for (int ct = 0; ct < 8; ++ct) {
            int fi = ct * 256 + fb;
            s16x8 wh1 = w1h[fi], wl1 = w1l[fi];
            s16x8 wh2 = w2h[fi], wl2 = w2l[fi];
            acc0[ct] = MFMA_BF16(a0, wh1, acc0[ct], 0, 0, 0);
            acc0[ct] = MFMA_BF16(a0, wl1, acc0[ct], 0, 0, 0);
            acc0[ct] = MFMA_BF16(b0, wh2, acc0[ct], 0, 0, 0);
            acc0[ct] = MFMA_BF16(b0, wl2, acc0[ct], 0, 0, 0);
            acc1[ct] = MFMA_BF16(a1, wh1, acc1[ct], 0, 0, 0);
            acc1[ct] = MFMA_BF16(a1, wl1, acc1[ct], 0, 0, 0);
            acc1[ct] = MFMA_BF16(b1, wh2, acc1[ct], 0, 0, 0);
            acc1[ct] = MFMA_BF16(b1, wl2, acc1[ct], 0, 0, 0);
        }
    }

    float p1s[8], p2s[8];
    int col0 = l & 15;
    int nb0 = n0 + w * 16 + (kh << 2);
    int nb1 = nb0 + 64;
#pragma unroll
    for (int ct = 0; ct < 8; ++ct) {
        float bj = bias[ct * 16 + col0];
        float s1 = 0.f, s2 = 0.f;
#pragma unroll
        for (int rr = 0; rr < 4; ++rr) {
            int n = nb0 + rr;
            float h = acc0[ct][rr] + bj;
            if (n < N_NODES) {
                OUTb[(size_t)n * DIM + ct * 16 + col0] = f2b(h);
                s1 += h; s2 += h * h;
            }
            n = nb1 + rr;
            h = acc1[ct][rr] + bj;
            if (n < N_NODES) {
                OUTb[(size_t)n * DIM + ct * 16 + col0] = f2b(h);
                s1 += h; s2 += h * h;
            }
        }
        p1s[ct] = s1; p2s[ct] = s2;
    }
    if (doBN) {
        __shared__ float red1[512];
        __shared__ float red2[512];
#pragma unroll
        for (int ct = 0; ct < 8; ++ct) {
            p1s[ct] += __shfl_xor(p1s[ct], 16);
            p1s[ct] += __shfl_xor(p1s[ct], 32);
            p2s[ct] += __shfl_xor(p2s[ct], 16);
            p2s[ct] += __shfl_xor(p2s[ct], 32);
        }
        if (l < 16) {
#pragma unroll
            for (int ct = 0; ct < 8; ++ct) {
                red1[w * 128 + ct * 16 + l] = p1s[ct];
                red2[w * 128 + ct * 16 + l] = p2s[ct];
            }
        }
        __syncthreads();
        if (t < 128) {
            float s1 = red1[t] + red1[128 + t] + red1[256 + t] + red1[384 + t];
            float s2 = red2[t] + red2[128 + t] + red2[256 + t] + red2[384 + t];
            atomicAdd(&bnacc[t], s1);
            atomicAdd(&bnacc[128 + t], s2);
        }
    }
}

// ---------------- fused pool (blocks 0..127) + projection (blocks 128..) ----
__global__ __launch_bounds__(256) void k_poolproj(
        const unsigned short* __restrict__ H1b, const int* __restrict__ batch,
        float* __restrict__ gout, const short* __restrict__ fWph,
        const short* __restrict__ fWpl, const float* __restrict__ bp,
        float* __restrict__ OUT) {
    int t = threadIdx.x;
    if (blockIdx.x < NG) {
        __shared__ float red[2][128];
        int g = blockIdx.x;
        int d = t & 127;
        int sl = t >> 7;
        int lo = 0, hi = N_NODES;
        while (lo < hi) { int m = (lo + hi) >> 1; if (batch[m] < g) lo = m + 1; else hi = m; }
        int s = lo;
        lo = 0; hi = N_NODES;
        while (lo < hi) { int m = (lo + hi) >> 1; if (batch[m] < g + 1) lo = m + 1; else hi = m; }
        int e = lo;
        float sum = 0.f;
        for (int n = s + sl; n < e; n += 2) sum += b2f(H1b[(size_t)n * DIM + d]);
        red[sl][d] = sum;
        __syncthreads();
        if (t < 128)
            gout[g * DIM + d] = (red[0][d] + red[1][d]) / (float)max(e - s, 1);
        return;
    }
    int w = t >> 6, l = t & 63;
    int n0 = (blockIdx.x - NG) * 128;
    int r = l & 15, kh = l >> 4;
    int row0 = n0 + w * 16 + r;
    int row1 = row0 + 64;
    int n_0 = min(row0, N_NODES - 1);
    int n_1 = min(row1, N_NODES - 1);
    f32x4 acc0[4], acc1[4];
#pragma unroll
    for (int ct = 0; ct < 4; ++ct) {
        acc0[ct] = (f32x4){0.f, 0.f, 0.f, 0.f};
        acc1[ct] = (f32x4){0.f, 0.f, 0.f, 0.f};
    }
    const s16x8* wph = (const s16x8*)fWph;
    const s16x8* wpl = (const s16x8*)fWpl;
#pragma unroll
    for (int ks = 0; ks < 4; ++ks) {
        int kb = ks * 32 + kh * 8;
        s16x8 r0 = *reinterpret_cast<const s16x8*>(&H1b[(size_t)n_0 * DIM + kb]);
        s16x8 r1 = *reinterpret_cast<const s16x8*>(&H1b[(size_t)n_1 * DIM + kb]);
        s16x8 a0, a1;
#pragma unroll
        for (int i = 0; i < 8; ++i) {
            a0[i] = r0[i] < 0 ? (short)0 : r0[i];
            a1[i] = r1[i] < 0 ? (short)0 : r1[i];
        }
        int fb = ks * 64 + l;
#pragma unroll
        for (int ct = 0; ct < 4; ++ct) {
            int fi = ct * 256 + fb;
            s16x8 wh = wph[fi], wl = wpl[fi];
            acc0[ct] = MFMA_BF16(a0, wh, acc0[ct], 0, 0, 0);
            acc0[ct] = MFMA_BF16(a0, wl, acc0[ct], 0, 0, 0);
            acc1[ct] = MFMA_BF16(a1, wh, acc1[ct], 0, 0, 0);
            acc1[ct] = MFMA_BF16(a1, wl, acc1[ct], 0, 0, 0);
        }
    }
    int col0 = l & 15;
    int nb0 = n0 + w * 16 + (kh << 2);
    int nb1 = nb0 + 64;
#pragma unroll
    for (int ct = 0; ct < 4; ++ct) {
        float bj = bp[ct * 16 + col0];
#pragma unroll
        for (int rr = 0; rr < 4; ++rr) {
            int n = nb0 + rr;
            if (n < N_NODES)
                OUT[(size_t)n * NCLS + ct * 16 + col0] = acc0[ct][rr] + bj;
            n = nb1 + rr;
            if (n < N_NODES)
                OUT[(size_t)n * NCLS + ct * 16 + col0] = acc1[ct][rr] + bj;
        }
    }
}

extern "C" void kernel_launch(void* const* d_in, const int* in_sizes, int n_in,
                              void* d_out, int out_size, void* d_ws, size_t ws_size,
                              hipStream_t stream) {
    (void)in_sizes; (void)n_in; (void)out_size;
    const float* x     = (const float*)d_in[0];
    const float* xe    = (const float*)d_in[1];
    const int*   eidx  = (const int*)d_in[2];
    const int*   batch = (const int*)d_in[3];
    const float* Wl0   = (const float*)d_in[4];
    const float* bl0   = (const float*)d_in[5];
    const float* Wr0   = (const float*)d_in[6];
    const float* Wl1   = (const float*)d_in[7];
    const float* bl1   = (const float*)d_in[8];
    const float* Wr1   = (const float*)d_in[9];
    const float* gamma0 = (const float*)d_in[10];
    const float* beta0  = (const float*)d_in[11];
    const float* Wp    = (const float*)d_in[12];
    const float* bp    = (const float*)d_in[13];
    const int* srcp = eidx;
    const int* dstp = eidx + N_EDGES;

    char* ws = (char*)d_ws;
    size_t off = 0;
    auto carve = [&](size_t bytes) {
        void* p = ws + off;
        off = (off + bytes + 255) & ~(size_t)255;
        return p;
    };
    int*   cnt    = (int*)carve((size_t)N_NODES * 4);
    int*   rowptr = (int*)carve((size_t)(N_NODES + 1) * 4);
    int*   wcur   = (int*)carve((size_t)N_NODES * 4);
    int*   bsums  = (int*)carve(128 * 4);
    float* bnacc  = (float*)carve(256 * 4);
    int2*  esort  = (int2*)carve((size_t)N_EDGES * 8);
    unsigned short* AGGb = (unsigned short*)carve((size_t)N_NODES * DIM * 2);
    unsigned short* x_bf = (unsigned short*)carve((size_t)N_NODES * DIM * 2);
    unsigned short* H_bf = (unsigned short*)carve((size_t)N_NODES * DIM * 2);
    unsigned short* H1b  = (unsigned short*)carve((size_t)N_NODES * DIM * 2);
    short* fWl0h = (short*)carve(16384 * 2);
    short* fWl0l = (short*)carve(16384 * 2);
    short* fWr0h = (short*)carve(16384 * 2);
    short* fWr0l = (short*)carve(16384 * 2);
    short* fWl1h = (short*)carve(16384 * 2);
    short* fWl1l = (short*)carve(16384 * 2);
    short* fWr1h = (short*)carve(16384 * 2);
    short* fWr1l = (short*)carve(16384 * 2);
    short* fWph  = (short*)carve(8192 * 2);
    short* fWpl  = (short*)carve(8192 * 2);

    size_t xes_bytes = (size_t)N_EDGES * DIM * 2;   // 409.6 MB
    int seq = (off + xes_bytes + 256 <= ws_size) ? 1 : 0;
    unsigned short* xe_s = seq ? (unsigned short*)carve(xes_bytes) : nullptr;

    float* out_h = (float*)d_out;
    float* out_g = out_h + (size_t)N_NODES * NCLS;

    hipMemsetAsync(cnt, 0, (size_t)N_NODES * 4, stream);

    // fused: bnacc zero | weight prep | x->bf16 | degree histogram
    k_mega0<<<36 + 6250 + 6250, 256, 0, stream>>>(
        Wl0, Wr0, Wl1, Wr1, Wp,
        fWl0h, fWl0l, fWr0h, fWr0l, fWl1h, fWl1l, fWr1h, fWr1l, fWph, fWpl,
        x, x_bf, dstp, cnt, bnacc);

    int nb = (N_NODES + 1023) / 1024;  // 98
    k_scan1<<<nb, 1024, 0, stream>>>(cnt, rowptr, bsums);
    k_scan2<<<1, 128, 0, stream>>>(bsums, nb);
    k_scan3<<<nb, 1024, 0, stream>>>(rowptr, bsums, wcur);
    k_scatter<<<(N_EDGES + 255) / 256, 256, 0, stream>>>(srcp, dstp, wcur, esort);

    int ablocks = (N_NODES * 64 + 255) / 256;   // 25000
    int gblocks = (N_NODES + 127) / 128;        // 782

    // layer 0: agg reads f32 xe (random), writes xe_s bf16 (sequential)
    if (seq)
        k_agg<0><<<ablocks, 256, 0, stream>>>(x_bf, xe, xe_s, rowptr, esort, AGGb,
                                              nullptr, nullptr, nullptr);
    else
        k_agg<2><<<ablocks, 256, 0, stream>>>(x_bf, xe, nullptr, rowptr, esort, AGGb,
                                              bnacc, gamma0, beta0);
    k_gemm2<<<gblocks, 256, 0, stream>>>(AGGb, x_bf, fWl0h, fWl0l, fWr0h, fWr0l,
                                         bl0, H_bf, bnacc, gamma0, beta0, 1, 0);

    // layer 1: agg reads xe_s sequentially, BN+relu fused (coeffs from bnacc)
    if (seq)
        k_agg<1><<<ablocks, 256, 0, stream>>>(H_bf, xe, xe_s, rowptr, esort, AGGb,
                                              bnacc, gamma0, beta0);
    else
        k_agg<2><<<ablocks, 256, 0, stream>>>(H_bf, xe, nullptr, rowptr, esort, AGGb,
                                              bnacc, gamma0, beta0);
    k_gemm2<<<gblocks, 256, 0, stream>>>(AGGb, H_bf, fWl1h, fWl1l, fWr1h, fWr1l,
                                         bl1, H1b, bnacc, gamma0, beta0, 0, 1);

    // readout: pool + proj in one launch
    k_poolproj<<<NG + gblocks, 256, 0, stream>>>(H1b, batch, out_g,
                                                 fWph, fWpl, bp, out_h);
}

// Round 13
// 851.339 us; speedup vs baseline: 1.4145x; 1.0028x over previous
//
#include <hip/hip_runtime.h>

#define N_NODES 100000
#define N_EDGES 1600000
#define DIM 128
#define NCLS 64
#define NG 128
#define BN_EPS 1e-5f

typedef __attribute__((ext_vector_type(8))) short s16x8;
typedef __attribute__((ext_vector_type(4))) float f32x4;
#define MFMA_BF16 __builtin_amdgcn_mfma_f32_16x16x32_bf16

// f32 -> bf16 RNE
__device__ __forceinline__ unsigned short f2b(float x) {
    unsigned u = __float_as_uint(x);
    return (unsigned short)((u + 0x7FFFu + ((u >> 16) & 1u)) >> 16);
}
__device__ __forceinline__ float b2f(unsigned short s) {
    return __uint_as_float(((unsigned)s) << 16);
}
__device__ __forceinline__ float4 bexp4(ushort4 u) {
    float4 f;
    f.x = b2f(u.x); f.y = b2f(u.y); f.z = b2f(u.z); f.w = b2f(u.w);
    return f;
}

// nontemporal float4 load via clang ext_vector (builtin requires vector-of-scalar)
__device__ __forceinline__ float4 ntload4(const float* p) {
    f32x4 v = __builtin_nontemporal_load(reinterpret_cast<const f32x4*>(p));
    float4 r;
    r.x = v[0]; r.y = v[1]; r.z = v[2]; r.w = v[3];
    return r;
}

// split 8 f32 into bf16 hi + bf16 lo (truncation)
__device__ __forceinline__ void f2hl8(float4 v0, float4 v1, s16x8& h8, s16x8& l8) {
    float vv[8] = {v0.x, v0.y, v0.z, v0.w, v1.x, v1.y, v1.z, v1.w};
#pragma unroll
    for (int i = 0; i < 8; ++i) {
        unsigned u = __float_as_uint(vv[i]);
        short h = (short)(u >> 16);
        float r = vv[i] - __uint_as_float(u & 0xFFFF0000u);
        short l = (short)(__float_as_uint(r) >> 16);
        h8[i] = h;
        l8[i] = l;
    }
}

// ---------------- mega kernel 0: wprep(36) | cvt x->x_bf(6250) | hist(6250) ----
// also zeroes bnacc (block 0)
__global__ __launch_bounds__(256) void k_mega0(
        const float* __restrict__ Wl0, const float* __restrict__ Wr0,
        const float* __restrict__ Wl1, const float* __restrict__ Wr1,
        const float* __restrict__ Wp,
        short* __restrict__ fWl0h, short* __restrict__ fWl0l,
        short* __restrict__ fWr0h, short* __restrict__ fWr0l,
        short* __restrict__ fWl1h, short* __restrict__ fWl1l,
        short* __restrict__ fWr1h, short* __restrict__ fWr1l,
        short* __restrict__ fWph, short* __restrict__ fWpl,
        const float* __restrict__ x, unsigned short* __restrict__ x_bf,
        const int* __restrict__ dst, int* __restrict__ cnt,
        float* __restrict__ bnacc) {
    int b = blockIdx.x;
    if (b == 0) bnacc[threadIdx.x] = 0.f;
    if (b < 36) {
        const float* W; short* hi; short* lo; int ct;
        if (b < 8)       { W = Wl0; hi = fWl0h; lo = fWl0l; ct = b; }
        else if (b < 16) { W = Wr0; hi = fWr0h; lo = fWr0l; ct = b - 8; }
        else if (b < 24) { W = Wl1; hi = fWl1h; lo = fWl1l; ct = b - 16; }
        else if (b < 32) { W = Wr1; hi = fWr1h; lo = fWr1l; ct = b - 24; }
        else             { W = Wp;  hi = fWph;  lo = fWpl;  ct = b - 32; }
        if (b >= 32 && ct >= 4) return;
        int tt = threadIdx.x;
        int lane = tt & 63, ks = (tt >> 6) & 3;
        int row = ct * 16 + (lane & 15);
        int k0 = ks * 32 + ((lane >> 4) << 3);
        float4 v0 = *reinterpret_cast<const float4*>(&W[(size_t)row * DIM + k0]);
        float4 v1 = *reinterpret_cast<const float4*>(&W[(size_t)row * DIM + k0 + 4]);
        s16x8 h8, l8;
        f2hl8(v0, v1, h8, l8);
        int t = ct * 256 + ks * 64 + lane;
        *reinterpret_cast<s16x8*>(&hi[(size_t)t * 8]) = h8;
        *reinterpret_cast<s16x8*>(&lo[(size_t)t * 8]) = l8;
    } else if (b < 36 + 6250) {
        int i = (b - 36) * 256 + threadIdx.x;   // float8 index, exactly 1.6M
        float4 a = reinterpret_cast<const float4*>(x)[(size_t)i * 2];
        float4 c = reinterpret_cast<const float4*>(x)[(size_t)i * 2 + 1];
        ushort4 oa, ob;
        oa.x = f2b(a.x); oa.y = f2b(a.y); oa.z = f2b(a.z); oa.w = f2b(a.w);
        ob.x = f2b(c.x); ob.y = f2b(c.y); ob.z = f2b(c.z); ob.w = f2b(c.w);
        reinterpret_cast<ushort4*>(x_bf)[(size_t)i * 2] = oa;
        reinterpret_cast<ushort4*>(x_bf)[(size_t)i * 2 + 1] = ob;
    } else {
        int e = (b - 36 - 6250) * 256 + threadIdx.x;  // exactly 1.6M
        atomicAdd(&cnt[dst[e]], 1);
    }
}

// ---------------- exclusive scan (3 kernels) ----------------
__global__ void k_scan1(const int* __restrict__ cnt, int* __restrict__ rowptr,
                        int* __restrict__ bsums) {
    __shared__ int sd[1024];
    int tid = threadIdx.x;
    int i = blockIdx.x * 1024 + tid;
    int v = (i < N_NODES) ? cnt[i] : 0;
    sd[tid] = v;
    __syncthreads();
    for (int off = 1; off < 1024; off <<= 1) {
        int t2 = (tid >= off) ? sd[tid - off] : 0;
        __syncthreads();
        sd[tid] += t2;
        __syncthreads();
    }
    if (i < N_NODES) rowptr[i] = sd[tid] - v;
    if (tid == 1023) bsums[blockIdx.x] = sd[tid];
}

__global__ void k_scan2(int* __restrict__ bsums, int nb) {
    __shared__ int sd[128];
    int t = threadIdx.x;
    int v = (t < nb) ? bsums[t] : 0;
    sd[t] = v;
    __syncthreads();
    for (int off = 1; off < 128; off <<= 1) {
        int u = (t >= off) ? sd[t - off] : 0;
        __syncthreads();
        sd[t] += u;
        __syncthreads();
    }
    if (t < nb) bsums[t] = sd[t] - v;
}

__global__ void k_scan3(int* __restrict__ rowptr, const int* __restrict__ bsums,
                        int* __restrict__ wcur) {
    int i = blockIdx.x * 1024 + threadIdx.x;
    if (i < N_NODES) {
        int v = rowptr[i] + bsums[blockIdx.x];
        rowptr[i] = v;
        wcur[i] = v;
    }
    if (i == N_NODES - 1) rowptr[N_NODES] = N_EDGES;
}

// ---------------- bucket edges by dst ----------------
__global__ void k_scatter(const int* __restrict__ src, const int* __restrict__ dst,
                          int* __restrict__ wcur, int2* __restrict__ esort) {
    int e = blockIdx.x * 256 + threadIdx.x;
    if (e < N_EDGES) {
        int d = dst[e];
        int p = atomicAdd(&wcur[d], 1);
        esort[p] = make_int2(e, src[e]);
    }
}

// ---------------- gather-aggregate: one wave/node, 128-thread blocks --------
// esort hoisted via lanes 0..7 + shfl; next trip's esort load pipelined.
// MODE 0: read f32 xe random NONTEMPORAL, WRITE xe_s bf16 sequential, no BN.
// MODE 1: read xe_s bf16 sequential, BN+relu on gathered F (BN from bnacc).
// MODE 2: fallback, read f32 xe random nontemporal, BN+relu on gathered F.
template <int MODE>
__global__ __launch_bounds__(128) void k_agg(
        const unsigned short* __restrict__ Fb, const float* __restrict__ xe,
        unsigned short* __restrict__ xe_s,
        const int* __restrict__ rowptr, const int2* __restrict__ esort,
        unsigned short* __restrict__ agg, const float* __restrict__ bnacc,
        const float* __restrict__ gamma, const float* __restrict__ beta) {
    int wid = (blockIdx.x * 128 + threadIdx.x) >> 6;
    int lane = threadIdx.x & 63;
    if (wid >= N_NODES) return;
    int half = lane >> 5;
    int l = lane & 31;
    int p0 = rowptr[wid], p1 = rowptr[wid + 1];
    if (p0 == p1) {
        if (half == 0) {
            ushort4 z = make_ushort4(0, 0, 0, 0);
            *reinterpret_cast<ushort4*>(&agg[(size_t)wid * DIM + l * 4]) = z;
        }
        return;
    }
    float scv[4], shv[4];
    if (MODE != 0) {
#pragma unroll
        for (int i = 0; i < 4; ++i) {
            int d = l * 4 + i;
            float mu = bnacc[d] * (1.f / N_NODES);
            float var = bnacc[128 + d] * (1.f / N_NODES) - mu * mu;
            float rstd = rsqrtf(var + BN_EPS);
            scv[i] = gamma[d] * rstd;
            shv[i] = beta[d] - mu * scv[i];
        }
    }
    float4 acc = make_float4(0.f, 0.f, 0.f, 0.f);
    int2 ev = esort[min(p0 + (lane & 7), p1 - 1)];
    for (int p = p0; p < p1; p += 8) {
        int pn = p + 8;
        int2 evn;
        if (pn < p1) evn = esort[min(pn + (lane & 7), p1 - 1)];
#pragma unroll
        for (int j = 0; j < 4; ++j) {
            int k = j * 2 + half;     // entry index within trip, 0..7
            int q = p + k;
            int esx = __shfl(ev.x, k);
            int esy = __shfl(ev.y, k);
            float4 a = bexp4(*reinterpret_cast<const ushort4*>(
                &Fb[(size_t)esy * DIM + l * 4]));
            float4 b;
            if (MODE == 1) {
                int qc = min(q, p1 - 1);
                b = bexp4(*reinterpret_cast<const ushort4*>(
                    &xe_s[(size_t)qc * DIM + l * 4]));
            } else {
                b = ntload4(&xe[(size_t)esx * DIM + l * 4]);
            }
            if (MODE != 0) {
                a.x = fmaxf(a.x * scv[0] + shv[0], 0.f);
                a.y = fmaxf(a.y * scv[1] + shv[1], 0.f);
                a.z = fmaxf(a.z * scv[2] + shv[2], 0.f);
                a.w = fmaxf(a.w * scv[3] + shv[3], 0.f);
            }
            if (q < p1) {
                if (MODE == 0) {
                    ushort4 o;
                    o.x = f2b(b.x); o.y = f2b(b.y);
                    o.z = f2b(b.z); o.w = f2b(b.w);
                    *reinterpret_cast<ushort4*>(&xe_s[(size_t)q * DIM + l * 4]) = o;
                }
                acc.x += fmaxf(a.x + b.x, 0.f);
                acc.y += fmaxf(a.y + b.y, 0.f);
                acc.z += fmaxf(a.z + b.z, 0.f);
                acc.w += fmaxf(a.w + b.w, 0.f);
            }
        }
        if (pn < p1) ev = evn;
    }
    acc.x += __shfl_xor(acc.x, 32);
    acc.y += __shfl_xor(acc.y, 32);
    acc.z += __shfl_xor(acc.z, 32);
    acc.w += __shfl_xor(acc.w, 32);
    if (half == 0) {
        float s = 1.f / (float)(p1 - p0);
        ushort4 o;
        o.x = f2b(acc.x * s); o.y = f2b(acc.y * s);
        o.z = f2b(acc.z * s); o.w = f2b(acc.w * s);
        *reinterpret_cast<ushort4*>(&agg[(size_t)wid * DIM + l * 4]) = o;
    }
}

// ---------------- MFMA dual GEMM: OUT = Abf@W1^T + bn?(Bbf)@W2^T + bias ------
__global__ __launch_bounds__(256) void k_gemm2(
        const unsigned short* __restrict__ Abf, const unsigned short* __restrict__ Bbf,
        const short* __restrict__ fW1h, const short* __restrict__ fW1l,
        const short* __restrict__ fW2h, const short* __restrict__ fW2l,
        const float* __restrict__ bias, unsigned short* __restrict__ OUTb,
        float* __restrict__ bnacc, const float* __restrict__ gamma,
        const float* __restrict__ beta, int doBN, int bnB) {
    __shared__ float bnsc_s[256];
    int t = threadIdx.x, w = t >> 6, l = t & 63;
    if (bnB) {
        if (t < 128) {
            float mu = bnacc[t] * (1.f / N_NODES);
            float var = bnacc[128 + t] * (1.f / N_NODES) - mu * mu;
            float rstd = rsqrtf(var + BN_EPS);
            float sc = gamma[t] * rstd;
            bnsc_s[t] = sc;
            bnsc_s[128 + t] = beta[t] - mu * sc;
        }
        __syncthreads();
    }
    int n0 = blockIdx.x * 128;
    int r = l & 15, kh = l >> 4;
    int row0 = n0 + w * 16 + r;
    int row1 = row0 + 64;
    int n_0 = min(row0, N_NODES - 1);
    int n_1 = min(row1, N_NODES - 1);

    f32x4 acc0[8], acc1[8];
#pragma unroll
    for (int ct = 0; ct < 8; ++ct) {
        acc0[ct] = (f32x4){0.f, 0.f, 0.f, 0.f};
        acc1[ct] = (f32x4){0.f, 0.f, 0.f, 0.f};
    }
    const s16x8* w1h = (const s16x8*)fW1h;
    const s16x8* w1l = (const s16x8*)fW1l;
    const s16x8* w2h = (const s16x8*)fW2h;
    const s16x8* w2l = (const s16x8*)fW2l;

#pragma unroll
    for (int ks = 0; ks < 4; ++ks) {
        int kb = ks * 32 + kh * 8;
        s16x8 a0 = *reinterpret_cast<const s16x8*>(&Abf[(size_t)n_0 * DIM + kb]);
        s16x8 a1 = *reinterpret_cast<const s16x8*>(&Abf[(size_t)n_1 * DIM + kb]);
        s16x8 b0 = *reinterpret_cast<const s16x8*>(&Bbf[(size_t)n_0 * DIM + kb]);
        s16x8 b1 = *reinterpret_cast<const s16x8*>(&Bbf[(size_t)n_1 * DIM + kb]);
        if (bnB) {
#pragma unroll
            for (int i = 0; i < 8; ++i) {
                int d = kb + i;
                float v = b2f((unsigned short)b0[i]);
                b0[i] = (short)f2b(fmaxf(v * bnsc_s[d] + bnsc_s[128 + d], 0.f));
                v = b2f((unsigned short)b1[i]);
                b1[i] = (short)f2b(fmaxf(v * bnsc_s[d] + bnsc_s[128 + d], 0.f));
            }
        }
        int fb = ks * 64 + l;
#pragma unroll
        for (int ct = 0; ct < 8; ++ct) {
            int fi = ct * 256 + fb;
            s16x8 wh1 = w1h[fi], wl1 = w1l[fi];
            s16x8 wh2 = w2h[fi], wl2 = w2l[fi];
            acc0[ct] = MFMA_BF16(a0, wh1, acc0[ct], 0, 0, 0);
            acc0[ct] = MFMA_BF16(a0, wl1, acc0[ct], 0, 0, 0);
            acc0[ct] = MFMA_BF16(b0, wh2, acc0[ct], 0, 0, 0);
            acc0[ct] = MFMA_BF16(b0, wl2, acc0[ct], 0, 0, 0);
            acc1[ct] = MFMA_BF16(a1, wh1, acc1[ct], 0, 0, 0);
            acc1[ct] = MFMA_BF16(a1, wl1, acc1[ct], 0, 0, 0);
            acc1[ct] = MFMA_BF16(b1, wh2, acc1[ct], 0, 0, 0);
            acc1[ct] = MFMA_BF16(b1, wl2, acc1[ct], 0, 0, 0);
        }
    }

    float p1s[8], p2s[8];
    int col0 = l & 15;
    int nb0 = n0 + w * 16 + (kh << 2);
    int nb1 = nb0 + 64;
#pragma unroll
    for (int ct = 0; ct < 8; ++ct) {
        float bj = bias[ct * 16 + col0];
        float s1 = 0.f, s2 = 0.f;
#pragma unroll
        for (int rr = 0; rr < 4; ++rr) {
            int n = nb0 + rr;
            float h = acc0[ct][rr] + bj;
            if (n < N_NODES) {
                OUTb[(size_t)n * DIM + ct * 16 + col0] = f2b(h);
                s1 += h; s2 += h * h;
            }
            n = nb1 + rr;
            h = acc1[ct][rr] + bj;
            if (n < N_NODES) {
                OUTb[(size_t)n * DIM + ct * 16 + col0] = f2b(h);
                s1 += h; s2 += h * h;
            }
        }
        p1s[ct] = s1; p2s[ct] = s2;
    }
    if (doBN) {
        __shared__ float red1[512];
        __shared__ float red2[512];
#pragma unroll
        for (int ct = 0; ct < 8; ++ct) {
            p1s[ct] += __shfl_xor(p1s[ct], 16);
            p1s[ct] += __shfl_xor(p1s[ct], 32);
            p2s[ct] += __shfl_xor(p2s[ct], 16);
            p2s[ct] += __shfl_xor(p2s[ct], 32);
        }
        if (l < 16) {
#pragma unroll
            for (int ct = 0; ct < 8; ++ct) {
                red1[w * 128 + ct * 16 + l] = p1s[ct];
                red2[w * 128 + ct * 16 + l] = p2s[ct];
            }
        }
        __syncthreads();
        if (t < 128) {
            float s1 = red1[t] + red1[128 + t] + red1[256 + t] + red1[384 + t];
            float s2 = red2[t] + red2[128 + t] + red2[256 + t] + red2[384 + t];
            atomicAdd(&bnacc[t], s1);
            atomicAdd(&bnacc[128 + t], s2);
        }
    }
}

// ---------------- fused pool (blocks 0..127) + projection (blocks 128..) ----
__global__ __launch_bounds__(256) void k_poolproj(
        const unsigned short* __restrict__ H1b, const int* __restrict__ batch,
        float* __restrict__ gout, const short* __restrict__ fWph,
        const short* __restrict__ fWpl, const float* __restrict__ bp,
        float* __restrict__ OUT) {
    int t = threadIdx.x;
    if (blockIdx.x < NG) {
        __shared__ float red[2][128];
        int g = blockIdx.x;
        int d = t & 127;
        int sl = t >> 7;
        int lo = 0, hi = N_NODES;
        while (lo < hi) { int m = (lo + hi) >> 1; if (batch[m] < g) lo = m + 1; else hi = m; }
        int s = lo;
        lo = 0; hi = N_NODES;
        while (lo < hi) { int m = (lo + hi) >> 1; if (batch[m] < g + 1) lo = m + 1; else hi = m; }
        int e = lo;
        float sum = 0.f;
        for (int n = s + sl; n < e; n += 2) sum += b2f(H1b[(size_t)n * DIM + d]);
        red[sl][d] = sum;
        __syncthreads();
        if (t < 128)
            gout[g * DIM + d] = (red[0][d] + red[1][d]) / (float)max(e - s, 1);
        return;
    }
    int w = t >> 6, l = t & 63;
    int n0 = (blockIdx.x - NG) * 128;
    int r = l & 15, kh = l >> 4;
    int row0 = n0 + w * 16 + r;
    int row1 = row0 + 64;
    int n_0 = min(row0, N_NODES - 1);
    int n_1 = min(row1, N_NODES - 1);
    f32x4 acc0[4], acc1[4];
#pragma unroll
    for (int ct = 0; ct < 4; ++ct) {
        acc0[ct] = (f32x4){0.f, 0.f, 0.f, 0.f};
        acc1[ct] = (f32x4){0.f, 0.f, 0.f, 0.f};
    }
    const s16x8* wph = (const s16x8*)fWph;
    const s16x8* wpl = (const s16x8*)fWpl;
#pragma unroll
    for (int ks = 0; ks < 4; ++ks) {
        int kb = ks * 32 + kh * 8;
        s16x8 r0 = *reinterpret_cast<const s16x8*>(&H1b[(size_t)n_0 * DIM + kb]);
        s16x8 r1 = *reinterpret_cast<const s16x8*>(&H1b[(size_t)n_1 * DIM + kb]);
        s16x8 a0, a1;
#pragma unroll
        for (int i = 0; i < 8; ++i) {
            a0[i] = r0[i] < 0 ? (short)0 : r0[i];
            a1[i] = r1[i] < 0 ? (short)0 : r1[i];
        }
        int fb = ks * 64 + l;
#pragma unroll
        for (int ct = 0; ct < 4; ++ct) {
            int fi = ct * 256 + fb;
            s16x8 wh = wph[fi], wl = wpl[fi];
            acc0[ct] = MFMA_BF16(a0, wh, acc0[ct], 0, 0, 0);
            acc0[ct] = MFMA_BF16(a0, wl, acc0[ct], 0, 0, 0);
            acc1[ct] = MFMA_BF16(a1, wh, acc1[ct], 0, 0, 0);
            acc1[ct] = MFMA_BF16(a1, wl, acc1[ct], 0, 0, 0);
        }
    }
    int col0 = l & 15;
    int nb0 = n0 + w * 16 + (kh << 2);
    int nb1 = nb0 + 64;
#pragma unroll
    for (int ct = 0; ct < 4; ++ct) {
        float bj = bp[ct * 16 + col0];
#pragma unroll
        for (int rr = 0; rr < 4; ++rr) {
            int n = nb0 + rr;
            if (n < N_NODES)
                OUT[(size_t)n * NCLS + ct * 16 + col0] = acc0[ct][rr] + bj;
            n = nb1 + rr;
            if (n < N_NODES)
                OUT[(size_t)n * NCLS + ct * 16 + col0] = acc1[ct][rr] + bj;
        }
    }
}

extern "C" void kernel_launch(void* const* d_in, const int* in_sizes, int n_in,
                              void* d_out, int out_size, void* d_ws, size_t ws_size,
                              hipStream_t stream) {
    (void)in_sizes; (void)n_in; (void)out_size;
    const float* x     = (const float*)d_in[0];
    const float* xe    = (const float*)d_in[1];
    const int*   eidx  = (const int*)d_in[2];
    const int*   batch = (const int*)d_in[3];
    const float* Wl0   = (const float*)d_in[4];
    const float* bl0   = (const float*)d_in[5];
    const float* Wr0   = (const float*)d_in[6];
    const float* Wl1   = (const float*)d_in[7];
    const float* bl1   = (const float*)d_in[8];
    const float* Wr1   = (const float*)d_in[9];
    const float* gamma0 = (const float*)d_in[10];
    const float* beta0  = (const float*)d_in[11];
    const float* Wp    = (const float*)d_in[12];
    const float* bp    = (const float*)d_in[13];
    const int* srcp = eidx;
    const int* dstp = eidx + N_EDGES;

    char* ws = (char*)d_ws;
    size_t off = 0;
    auto carve = [&](size_t bytes) {
        void* p = ws + off;
        off = (off + bytes + 255) & ~(size_t)255;
        return p;
    };
    int*   cnt    = (int*)carve((size_t)N_NODES * 4);
    int*   rowptr = (int*)carve((size_t)(N_NODES + 1) * 4);
    int*   wcur   = (int*)carve((size_t)N_NODES * 4);
    int*   bsums  = (int*)carve(128 * 4);
    float* bnacc  = (float*)carve(256 * 4);
    int2*  esort  = (int2*)carve((size_t)N_EDGES * 8);
    unsigned short* AGGb = (unsigned short*)carve((size_t)N_NODES * DIM * 2);
    unsigned short* x_bf = (unsigned short*)carve((size_t)N_NODES * DIM * 2);
    unsigned short* H_bf = (unsigned short*)carve((size_t)N_NODES * DIM * 2);
    unsigned short* H1b  = (unsigned short*)carve((size_t)N_NODES * DIM * 2);
    short* fWl0h = (short*)carve(16384 * 2);
    short* fWl0l = (short*)carve(16384 * 2);
    short* fWr0h = (short*)carve(16384 * 2);
    short* fWr0l = (short*)carve(16384 * 2);
    short* fWl1h = (short*)carve(16384 * 2);
    short* fWl1l = (short*)carve(16384 * 2);
    short* fWr1h = (short*)carve(16384 * 2);
    short* fWr1l = (short*)carve(16384 * 2);
    short* fWph  = (short*)carve(8192 * 2);
    short* fWpl  = (short*)carve(8192 * 2);

    size_t xes_bytes = (size_t)N_EDGES * DIM * 2;   // 409.6 MB
    int seq = (off + xes_bytes + 256 <= ws_size) ? 1 : 0;
    unsigned short* xe_s = seq ? (unsigned short*)carve(xes_bytes) : nullptr;

    float* out_h = (float*)d_out;
    float* out_g = out_h + (size_t)N_NODES * NCLS;

    hipMemsetAsync(cnt, 0, (size_t)N_NODES * 4, stream);

    // fused: bnacc zero | weight prep | x->bf16 | degree histogram
    k_mega0<<<36 + 6250 + 6250, 256, 0, stream>>>(
        Wl0, Wr0, Wl1, Wr1, Wp,
        fWl0h, fWl0l, fWr0h, fWr0l, fWl1h, fWl1l, fWr1h, fWr1l, fWph, fWpl,
        x, x_bf, dstp, cnt, bnacc);

    int nb = (N_NODES + 1023) / 1024;  // 98
    k_scan1<<<nb, 1024, 0, stream>>>(cnt, rowptr, bsums);
    k_scan2<<<1, 128, 0, stream>>>(bsums, nb);
    k_scan3<<<nb, 1024, 0, stream>>>(rowptr, bsums, wcur);
    k_scatter<<<(N_EDGES + 255) / 256, 256, 0, stream>>>(srcp, dstp, wcur, esort);

    int ablocks = (N_NODES * 64 + 127) / 128;   // 50000 (2 waves/block)
    int gblocks = (N_NODES + 127) / 128;        // 782

    // layer 0: agg reads f32 xe (random, nontemporal), writes xe_s bf16 (seq)
    if (seq)
        k_agg<0><<<ablocks, 128, 0, stream>>>(x_bf, xe, xe_s, rowptr, esort, AGGb,
                                              nullptr, nullptr, nullptr);
    else
        k_agg<2><<<ablocks, 128, 0, stream>>>(x_bf, xe, nullptr, rowptr, esort, AGGb,
                                              bnacc, gamma0, beta0);
    k_gemm2<<<gblocks, 256, 0, stream>>>(AGGb, x_bf, fWl0h, fWl0l, fWr0h, fWr0l,
                                         bl0, H_bf, bnacc, gamma0, beta0, 1, 0);

    // layer 1: agg reads xe_s sequentially, BN+relu fused (coeffs from bnacc)
    if (seq)
        k_agg<1><<<ablocks, 128, 0, stream>>>(H_bf, xe, xe_s, rowptr, esort, AGGb,
                                              bnacc, gamma0, beta0);
    else
        k_agg<2><<<ablocks, 128, 0, stream>>>(H_bf, xe, nullptr, rowptr, esort, AGGb,
                                              bnacc, gamma0, beta0);
    k_gemm2<<<gblocks, 256, 0, stream>>>(AGGb, H_bf, fWl1h, fWl1l, fWr1h, fWr1l,
                                         bl1, H1b, bnacc, gamma0, beta0, 0, 1);

    // readout: pool + proj in one launch
    k_poolproj<<<NG + gblocks, 256, 0, stream>>>(H1b, batch, out_g,
                                                 fWph, fWpl, bp, out_h);
}